// Round 7
// baseline (319.882 us; speedup 1.0000x reference)
//
#include <hip/hip_runtime.h>
#include <hip/hip_bf16.h>

// LinearAttention: b=2, l=2048, d_model=1024, h=16, fd=16, hd=64
#define NH 16
#define FD 16
#define HD 64
#define BATCH 2
#define SEQ 2048
#define DM 1024
#define ROWS (BATCH * SEQ)   // 4096 token rows
#define CHUNK 128
#define NCH (SEQ / CHUNK)    // 16 chunks per sequence
#define NBH (BATCH * NH)     // 32 (b,h) pairs

typedef __hip_bfloat16 bf16;
typedef __attribute__((ext_vector_type(8))) short short8;  // 8 bf16 (MFMA A/B frag)
typedef __attribute__((ext_vector_type(4))) float f32x4;   // MFMA C/D frag

__device__ inline float bfbits(unsigned int h) {
  union { unsigned int u; float f; } c; c.u = h << 16; return c.f;
}
__device__ inline unsigned short f2bf(float x) {
  bf16 h = __float2bfloat16(x);
  return *(unsigned short*)&h;
}

// Flexible 8-element f32 fetch: idx must be a multiple of 8.
__device__ inline void load8(const void* src, size_t idx, int isf32, float* out) {
  if (isf32) {
    const float* p = (const float*)src + idx;
    float4 a = *(const float4*)p;
    float4 b = *(const float4*)(p + 4);
    out[0] = a.x; out[1] = a.y; out[2] = a.z; out[3] = a.w;
    out[4] = b.x; out[5] = b.y; out[6] = b.z; out[7] = b.w;
  } else {
    const uint4 w = *(const uint4*)((const unsigned short*)src + idx);
    out[0] = bfbits(w.x & 0xffffu); out[1] = bfbits(w.x >> 16);
    out[2] = bfbits(w.y & 0xffffu); out[3] = bfbits(w.y >> 16);
    out[4] = bfbits(w.z & 0xffffu); out[5] = bfbits(w.z >> 16);
    out[6] = bfbits(w.w & 0xffffu); out[7] = bfbits(w.w >> 16);
  }
}

// Async global->LDS, 16 bytes/lane. LDS dest is wave-uniform base + lane*16.
__device__ inline void gload16(const void* g, void* l) {
  __builtin_amdgcn_global_load_lds(
      (const __attribute__((address_space(1))) unsigned int*)g,
      (__attribute__((address_space(3))) unsigned int*)l, 16, 0, 0);
}

// ---------------------------------------------------------------------------
// Dtype detection (flag=1 means f32): low-16-bit-as-bf16 exponent statistic.
// ---------------------------------------------------------------------------
__global__ __launch_bounds__(256) void detect_dtype(const unsigned int* __restrict__ w,
                                                    int* __restrict__ flag) {
  __shared__ int red[256];
  int cnt = 0;
  for (int i = threadIdx.x; i < 4096; i += 256) {
    unsigned int e = (w[i] >> 7) & 0xFFu;
    cnt += (e >= 0x90u) ? 1 : 0;
  }
  red[threadIdx.x] = cnt;
  __syncthreads();
  for (int s = 128; s > 0; s >>= 1) {
    if (threadIdx.x < s) red[threadIdx.x] += red[threadIdx.x + s];
    __syncthreads();
  }
  if (threadIdx.x == 0) *flag = (red[0] > 64) ? 1 : 0;
}

// ---------------------------------------------------------------------------
// Combined q+k projection GEMM (one grid): C[4096,256] x2, f32 out,
// f64-absorbed f32 accumulation in groups of 4 k-steps.
// ACCURACY-CRITICAL: feeds z = 1/(q.cumsum(k)+eps). Per-output-element add
// order is BIT-IDENTICAL to rounds 4-6 (kt asc, kk 4-groups, j asc, f32
// in-group, f64 across) -> absmax pinned at 384. Do not alter the grouping.
// Round-6 lesson: bound by LDS *instruction* throughput (b128 ~ 12 cyc, 85
// B/cyc — not the 128 B/cyc bank peak). This round: micro-tile 8x4
// (12 b128 per 128 MACs = 1.5 B/MAC, 25% fewer LDS instrs + 25% fewer
// waves), BM=128 BN=64 BK=32, 256 thr, grid 32x8 = 256 blocks (1/CU), and
// register prefetch of the next k-tile's global loads so the single
// resident block hides global latency inside its compute phase.
// Bank layout: ar rows tx+16i -> 2-way + broadcast (free); br -> broadcast.
// ---------------------------------------------------------------------------
__global__ __launch_bounds__(256) void gemm_qk4(const void* __restrict__ A,
                                                const void* __restrict__ Wq,
                                                const void* __restrict__ Wk,
                                                const int* __restrict__ flagp,
                                                float* __restrict__ qf,
                                                float* __restrict__ kf) {
  const int isf32 = *flagp;
  __shared__ float As[128 * 36];  // row-major [m][k], stride 36 (16B mult)
  __shared__ float Bs[64 * 36];
  const int tid = threadIdx.x;
  const int m0 = blockIdx.x * 128;
  const int isK = blockIdx.y >> 2;          // y in [0,8): 0-3 q, 4-7 k
  const int n0 = (blockIdx.y & 3) * 64;
  const void* B = isK ? Wk : Wq;
  float* C = isK ? kf : qf;
  const int tx = tid & 15, ty = tid >> 4;   // micro-tile 8(m, stride 16) x 4(n)
  const int lmA = tid >> 1, lcA = (tid & 1) * 16;  // A loader: 128 rows x 2 halves
  const int lmB = tid >> 2, lcB = (tid & 3) * 8;   // B loader: 64 rows x 4 chunks
  double dacc[8][4];
#pragma unroll
  for (int i = 0; i < 8; ++i)
#pragma unroll
    for (int n = 0; n < 4; ++n) dacc[i][n] = 0.0;

  float av[16], bv[8];
  load8(A, (size_t)(m0 + lmA) * DM + lcA, isf32, &av[0]);
  load8(A, (size_t)(m0 + lmA) * DM + lcA + 8, isf32, &av[8]);
  load8(B, (size_t)(n0 + lmB) * DM + lcB, isf32, bv);

  for (int kt = 0; kt < DM; kt += 32) {
    __syncthreads();  // previous iter's LDS reads complete
    *(float4*)&As[lmA * 36 + lcA] = *(float4*)&av[0];
    *(float4*)&As[lmA * 36 + lcA + 4] = *(float4*)&av[4];
    *(float4*)&As[lmA * 36 + lcA + 8] = *(float4*)&av[8];
    *(float4*)&As[lmA * 36 + lcA + 12] = *(float4*)&av[12];
    *(float4*)&Bs[lmB * 36 + lcB] = *(float4*)&bv[0];
    *(float4*)&Bs[lmB * 36 + lcB + 4] = *(float4*)&bv[4];
    __syncthreads();
    if (kt + 32 < DM) {  // prefetch next tile into registers (latency hidden
                         // under the ~2800-cyc compute below)
      load8(A, (size_t)(m0 + lmA) * DM + kt + 32 + lcA, isf32, &av[0]);
      load8(A, (size_t)(m0 + lmA) * DM + kt + 32 + lcA + 8, isf32, &av[8]);
      load8(B, (size_t)(n0 + lmB) * DM + kt + 32 + lcB, isf32, bv);
    }
    for (int kk = 0; kk < 32; kk += 4) {
      float4 ar[8], br[4];
#pragma unroll
      for (int i = 0; i < 8; ++i) ar[i] = *(const float4*)&As[(tx + 16 * i) * 36 + kk];
#pragma unroll
      for (int n = 0; n < 4; ++n) br[n] = *(const float4*)&Bs[(ty * 4 + n) * 36 + kk];
      float facc[8][4] = {};
#pragma unroll
      for (int j = 0; j < 4; ++j) {
#pragma unroll
        for (int i = 0; i < 8; ++i) {
          float a = ((const float*)&ar[i])[j];
#pragma unroll
          for (int n = 0; n < 4; ++n)
            facc[i][n] += a * ((const float*)&br[n])[j];
        }
      }
#pragma unroll
      for (int i = 0; i < 8; ++i)
#pragma unroll
        for (int n = 0; n < 4; ++n) dacc[i][n] += (double)facc[i][n];
    }
  }
#pragma unroll
  for (int i = 0; i < 8; ++i) {
    int row = m0 + tx + 16 * i;
    float4 o;
    o.x = (float)dacc[i][0]; o.y = (float)dacc[i][1];
    o.z = (float)dacc[i][2]; o.w = (float)dacc[i][3];
    *(float4*)&C[(size_t)row * 256 + n0 + ty * 4] = o;
  }
}

// ---------------------------------------------------------------------------
// MFMA GEMM w/ LDS staging (m97 structure): C[4096,1024] = A @ B^T, K=1024.
// Block tile 128x64, BK=32, 4 waves (each 64 rows x 32 cols), single LDS
// buffer + 2 barriers, global_load_lds width=16 (bf16 fast path).
// MODE 0: v-proj (A flex dtype, C bf16). MODE 1: o-proj (A bf16, C flex).
// ---------------------------------------------------------------------------
template <int MODE>
__global__ __launch_bounds__(256) void gemm_mfma(const void* __restrict__ Ap,
                                                 const void* __restrict__ Bp,
                                                 const int* __restrict__ flagp,
                                                 void* __restrict__ Cp) {
  const int isf32 = *flagp;
  const int aF32 = (MODE == 0) ? isf32 : 0;
  const int bF32 = isf32;
  __shared__ unsigned short As[128 * 32];  // row-major, 32 bf16 (64B) per row
  __shared__ unsigned short Bs[64 * 32];
  const int tid = threadIdx.x;
  const int wave = tid >> 6, lane = tid & 63;
  const int m0 = blockIdx.x * 128, n0 = blockIdx.y * 64;
  const int lrow = lane >> 2, lch = (lane & 3) * 8;  // loader: 16 rows x 4 chunks
  const int wm = wave >> 1, wn = wave & 1;           // wave -> 64x32 subtile
  const int mlane = lane & 15, kgrp = lane >> 4;
  const unsigned short* Ab = (const unsigned short*)Ap;
  const unsigned short* Bb = (const unsigned short*)Bp;
  f32x4 acc[4][2];
#pragma unroll
  for (int t = 0; t < 4; ++t)
#pragma unroll
    for (int u = 0; u < 2; ++u) acc[t][u] = (f32x4){0.f, 0.f, 0.f, 0.f};

  for (int k0 = 0; k0 < DM; k0 += 32) {
    __syncthreads();  // previous iter's frag reads done before overwrite
    if (!aF32) {
      const int r0 = wave * 32;
#pragma unroll
      for (int j = 0; j < 2; ++j) {
        const void* g = Ab + (size_t)(m0 + r0 + j * 16 + lrow) * DM + k0 + lch;
        gload16(g, &As[(r0 + j * 16) * 32]);  // wave-uniform LDS base
      }
    } else {
      for (int c = tid; c < 512; c += 256) {
        int r = c >> 2, cc = (c & 3) * 8;
        float v8[8];
        load8(Ap, (size_t)(m0 + r) * DM + k0 + cc, 1, v8);
        unsigned int w[4];
#pragma unroll
        for (int g2 = 0; g2 < 4; ++g2)
          w[g2] = (unsigned)f2bf(v8[2 * g2]) | ((unsigned)f2bf(v8[2 * g2 + 1]) << 16);
        *(uint4*)&As[r * 32 + cc] = *(uint4*)w;
      }
    }
    if (!bF32) {
      const void* g = Bb + (size_t)(n0 + wave * 16 + lrow) * DM + k0 + lch;
      gload16(g, &Bs[(wave * 16) * 32]);
    } else {
      {
        int c = tid;  // 256 chunks, one per thread
        int r = c >> 2, cc = (c & 3) * 8;
        float v8[8];
        load8(Bp, (size_t)(n0 + r) * DM + k0 + cc, 1, v8);
        unsigned int w[4];
#pragma unroll
        for (int g2 = 0; g2 < 4; ++g2)
          w[g2] = (unsigned)f2bf(v8[2 * g2]) | ((unsigned)f2bf(v8[2 * g2 + 1]) << 16);
        *(uint4*)&Bs[r * 32 + cc] = *(uint4*)w;
      }
    }
    __syncthreads();  // drains vmcnt (global_load_lds) + lgkmcnt

    short8 af[4], bfr[2];
#pragma unroll
    for (int t = 0; t < 4; ++t)
      af[t] = *(const short8*)&As[(wm * 64 + t * 16 + mlane) * 32 + kgrp * 8];
#pragma unroll
    for (int u = 0; u < 2; ++u)
      bfr[u] = *(const short8*)&Bs[(wn * 32 + u * 16 + mlane) * 32 + kgrp * 8];
#pragma unroll
    for (int t = 0; t < 4; ++t)
#pragma unroll
      for (int u = 0; u < 2; ++u)
        acc[t][u] = __builtin_amdgcn_mfma_f32_16x16x32_bf16(af[t], bfr[u], acc[t][u], 0, 0, 0);
  }

#pragma unroll
  for (int t = 0; t < 4; ++t)
#pragma unroll
    for (int u = 0; u < 2; ++u)
#pragma unroll
      for (int r = 0; r < 4; ++r) {
        int row = m0 + wm * 64 + t * 16 + kgrp * 4 + r;
        int col = n0 + wn * 32 + u * 16 + mlane;
        float v = acc[t][u][r];
        if (MODE == 0) {
          ((unsigned short*)Cp)[(size_t)row * DM + col] = f2bf(v);
        } else if (isf32) {
          ((float*)Cp)[(size_t)row * DM + col] = v;
        } else {
          ((unsigned short*)Cp)[(size_t)row * DM + col] = f2bf(v);
        }
      }
}

// ---------------------------------------------------------------------------
// attn_intra: per (b,h,chunk): causal intra-chunk y (bf16 out), chunk state
// S_c = k^T v (f32), chunk k-sum (f64). Grid = 512, 256 threads.
// ---------------------------------------------------------------------------
__global__ __launch_bounds__(256) void attn_intra(const float* __restrict__ qf,
                                                  const float* __restrict__ kf,
                                                  const unsigned short* __restrict__ vfb,
                                                  unsigned short* __restrict__ yib,
                                                  float* __restrict__ Sc,
                                                  double* __restrict__ Kc) {
  __shared__ float qc[CHUNK][20];
  __shared__ float kc[CHUNK][20];
  __shared__ float vc[CHUNK][68];
  const int bh = blockIdx.x >> 4;
  const int c = blockIdx.x & 15;
  const int b = bh >> 4, h = bh & 15;
  const int bl = c * CHUNK;
  const int tid = threadIdx.x;

  for (int idx = tid; idx < CHUNK * FD / 4; idx += 256) {
    int r = idx >> 2, f4 = (idx & 3) * 4;
    size_t g = ((size_t)(b * SEQ + bl + r)) * (NH * FD) + h * FD + f4;
    *(float4*)&qc[r][f4] = *(const float4*)&qf[g];
    *(float4*)&kc[r][f4] = *(const float4*)&kf[g];
  }
  for (int idx = tid; idx < CHUNK * HD / 8; idx += 256) {
    int r = idx >> 3, e8 = (idx & 7) * 8;
    uint4 w = *(const uint4*)&vfb[((size_t)(b * SEQ + bl + r)) * (NH * HD) + h * HD + e8];
    vc[r][e8 + 0] = bfbits(w.x & 0xffffu); vc[r][e8 + 1] = bfbits(w.x >> 16);
    vc[r][e8 + 2] = bfbits(w.y & 0xffffu); vc[r][e8 + 3] = bfbits(w.y >> 16);
    vc[r][e8 + 4] = bfbits(w.z & 0xffffu); vc[r][e8 + 5] = bfbits(w.z >> 16);
    vc[r][e8 + 6] = bfbits(w.w & 0xffffu); vc[r][e8 + 7] = bfbits(w.w >> 16);
  }
  __syncthreads();

  const int p = tid >> 2;
  const int n0 = 2 * p, n1 = 2 * p + 1;
  const int e0 = (tid & 3) * 16;
  float q0r[16], q1r[16];
#pragma unroll
  for (int d = 0; d < 16; ++d) { q0r[d] = qc[n0][d]; q1r[d] = qc[n1][d]; }
  float y0[16], y1[16];
#pragma unroll
  for (int e = 0; e < 16; ++e) { y0[e] = 0.f; y1[e] = 0.f; }

  for (int m = 0; m <= n1; ++m) {
    float kd[16], vv[16];
#pragma unroll
    for (int d = 0; d < 16; ++d) kd[d] = kc[m][d];
#pragma unroll
    for (int e = 0; e < 16; ++e) vv[e] = vc[m][e0 + e];
    float d0 = 0.f, d1 = 0.f;
#pragma unroll
    for (int d = 0; d < 16; ++d) { d0 += q0r[d] * kd[d]; d1 += q1r[d] * kd[d]; }
    if (m > n0) d0 = 0.f;  // causal mask (only the m==n1 step)
#pragma unroll
    for (int e = 0; e < 16; ++e) { y0[e] += d0 * vv[e]; y1[e] += d1 * vv[e]; }
  }
  const size_t ybase = (size_t)bh * SEQ + bl;
  {
    unsigned int w[4];
#pragma unroll
    for (int g = 0; g < 4; ++g)
      w[g] = (unsigned)f2bf(y0[2 * g]) | ((unsigned)f2bf(y0[2 * g + 1]) << 16);
    *(uint4*)&yib[(ybase + n0) * HD + e0] = *(uint4*)w;
#pragma unroll
    for (int g = 0; g < 4; ++g)
      w[g] = (unsigned)f2bf(y0[8 + 2 * g]) | ((unsigned)f2bf(y0[9 + 2 * g]) << 16);
    *(uint4*)&yib[(ybase + n0) * HD + e0 + 8] = *(uint4*)w;
#pragma unroll
    for (int g = 0; g < 4; ++g)
      w[g] = (unsigned)f2bf(y1[2 * g]) | ((unsigned)f2bf(y1[2 * g + 1]) << 16);
    *(uint4*)&yib[(ybase + n1) * HD + e0] = *(uint4*)w;
#pragma unroll
    for (int g = 0; g < 4; ++g)
      w[g] = (unsigned)f2bf(y1[8 + 2 * g]) | ((unsigned)f2bf(y1[9 + 2 * g]) << 16);
    *(uint4*)&yib[(ybase + n1) * HD + e0 + 8] = *(uint4*)w;
  }

  float* Scp = Sc + ((size_t)bh * NCH + c) * (FD * HD);
  for (int idx = tid; idx < FD * HD; idx += 256) {
    int d = idx >> 6, e = idx & 63;
    float s = 0.f;
    for (int m = 0; m < CHUNK; ++m) s += kc[m][d] * vc[m][e];
    Scp[idx] = s;
  }
  if (tid < FD) {
    double ks = 0.0;
    for (int m = 0; m < CHUNK; ++m) ks += (double)kc[m][tid];
    Kc[((size_t)bh * NCH + c) * FD + tid] = ks;
  }
}

// Exclusive prefix over chunks of S_c (f32) and Kc (f64). Grid = NBH = 32.
__global__ __launch_bounds__(256) void scan_states(float* __restrict__ Sc,
                                                   double* __restrict__ Kc) {
  const int bh = blockIdx.x;
  const int tid = threadIdx.x;
  float4 acc = make_float4(0.f, 0.f, 0.f, 0.f);
  size_t base = (size_t)bh * NCH * (FD * HD) + (size_t)tid * 4;
  for (int c = 0; c < NCH; ++c) {
    float4* p = (float4*)(Sc + base + (size_t)c * (FD * HD));
    float4 v = *p;
    *p = acc;
    acc.x += v.x; acc.y += v.y; acc.z += v.z; acc.w += v.w;
  }
  if (tid < FD) {
    double a = 0.0;
    for (int c = 0; c < NCH; ++c) {
      size_t i = ((size_t)bh * NCH + c) * FD + tid;
      double t = Kc[i];
      Kc[i] = a;
      a += t;
    }
  }
}

// ---------------------------------------------------------------------------
// attn_finish: y = (y_intra + q @ S_prev) * z, z = 1/(q.cumsum(k)+eps) in f64.
// Emits bf16 y in [b,l,h*hd] layout. Grid = 512.
// ---------------------------------------------------------------------------
__global__ __launch_bounds__(256) void attn_finish(const float* __restrict__ qf,
                                                   const float* __restrict__ kf,
                                                   const unsigned short* __restrict__ yib,
                                                   const float* __restrict__ Sc,
                                                   const double* __restrict__ Kc,
                                                   unsigned short* __restrict__ yob) {
  __shared__ float qc[CHUNK][20];
  __shared__ float kc[CHUNK][20];
  __shared__ float Sp[FD][HD];
  __shared__ double cs[CHUNK][17];
  __shared__ double zl[CHUNK];
  __shared__ double ksp[FD];
  const int bh = blockIdx.x >> 4;
  const int c = blockIdx.x & 15;
  const int b = bh >> 4, h = bh & 15;
  const int bl = c * CHUNK;
  const int tid = threadIdx.x;

  for (int idx = tid; idx < CHUNK * FD / 4; idx += 256) {
    int r = idx >> 2, f4 = (idx & 3) * 4;
    size_t g = ((size_t)(b * SEQ + bl + r)) * (NH * FD) + h * FD + f4;
    *(float4*)&qc[r][f4] = *(const float4*)&qf[g];
    *(float4*)&kc[r][f4] = *(const float4*)&kf[g];
  }
  const float* Scp = Sc + ((size_t)bh * NCH + c) * (FD * HD);
  for (int idx = tid; idx < FD * HD / 4; idx += 256) {
    int d = idx >> 4, e4 = (idx & 15) * 4;
    *(float4*)&Sp[d][e4] = *(const float4*)&Scp[(size_t)d * HD + e4];
  }
  if (tid < FD) ksp[tid] = Kc[((size_t)bh * NCH + c) * FD + tid];
  __syncthreads();

  if (tid < FD) {
    double run = ksp[tid];
    for (int m = 0; m < CHUNK; ++m) {
      run += (double)kc[m][tid];
      cs[m][tid] = run;
    }
  }
  __syncthreads();
  if (tid < CHUNK) {
    double dn = 0.0;
#pragma unroll
    for (int d = 0; d < 16; ++d) dn += (double)qc[tid][d] * cs[tid][d];
    zl[tid] = 1.0 / (dn + 1e-12);
  }
  __syncthreads();

  for (int idx = tid; idx < CHUNK * HD / 8; idx += 256) {
    int n = idx >> 3, e8 = (idx & 7) * 8;
    uint4 w = *(const uint4*)&yib[((size_t)bh * SEQ + bl + n) * HD + e8];
    float yv[8] = {bfbits(w.x & 0xffffu), bfbits(w.x >> 16),
                   bfbits(w.y & 0xffffu), bfbits(w.y >> 16),
                   bfbits(w.z & 0xffffu), bfbits(w.z >> 16),
                   bfbits(w.w & 0xffffu), bfbits(w.w >> 16)};
    double z = zl[n];
    unsigned int o[4];
#pragma unroll
    for (int jp = 0; jp < 4; ++jp) {
      int e = e8 + 2 * jp;
      float i0 = 0.f, i1 = 0.f;
#pragma unroll
      for (int d = 0; d < 16; ++d) {
        i0 += qc[n][d] * Sp[d][e];
        i1 += qc[n][d] * Sp[d][e + 1];
      }
      float r0 = (float)(((double)(yv[2 * jp] + i0)) * z);
      float r1 = (float)(((double)(yv[2 * jp + 1] + i1)) * z);
      o[jp] = (unsigned)f2bf(r0) | ((unsigned)f2bf(r1) << 16);
    }
    *(uint4*)&yob[((size_t)(b * SEQ + bl + n)) * (NH * HD) + h * HD + e8] = *(uint4*)o;
  }
}

extern "C" void kernel_launch(void* const* d_in, const int* in_sizes, int n_in,
                              void* d_out, int out_size, void* d_ws, size_t ws_size,
                              hipStream_t stream) {
  (void)in_sizes; (void)n_in; (void)out_size; (void)ws_size;
  const void* hs = d_in[0];
  const void* Wq = d_in[1];
  const void* Wk = d_in[2];
  const void* Wv = d_in[3];
  const void* Wo = d_in[4];

  // workspace (26.1 MB, proven safe; 42 MB NaN'd in round 1 — do not grow):
  // qf 4M | kf 4M | vfb/yob 8M (alias; v dead after attn_intra) | yib 8M |
  // Sc 2M | Kc 64K | flag
  char* ws = (char*)d_ws;
  float* qf = (float*)(ws);
  float* kf = (float*)(ws + (4u << 20));
  unsigned short* vfb = (unsigned short*)(ws + (8u << 20));
  unsigned short* yob = vfb;
  unsigned short* yib = (unsigned short*)(ws + (16u << 20));
  float* Sc = (float*)(ws + (24u << 20));
  double* Kc = (double*)(ws + (26u << 20));
  int* flag = (int*)(ws + (26u << 20) + 65536);

  detect_dtype<<<1, 256, 0, stream>>>((const unsigned int*)hs, flag);
  gemm_qk4<<<dim3(ROWS / 128, 8), 256, 0, stream>>>(hs, Wq, Wk, flag, qf, kf);
  gemm_mfma<0><<<dim3(ROWS / 128, 1024 / 64), 256, 0, stream>>>(hs, Wv, flag, vfb);
  attn_intra<<<NBH * NCH, 256, 0, stream>>>(qf, kf, vfb, yib, Sc, Kc);
  scan_states<<<NBH, 256, 0, stream>>>(Sc, Kc);
  attn_finish<<<NBH * NCH, 256, 0, stream>>>(qf, kf, yib, Sc, Kc, yob);
  gemm_mfma<1><<<dim3(ROWS / 128, 1024 / 64), 256, 0, stream>>>(yob, Wo, flag, d_out);
}

// Round 8
// 298.583 us; speedup vs baseline: 1.0713x; 1.0713x over previous
//
#include <hip/hip_runtime.h>
#include <hip/hip_bf16.h>

// LinearAttention: b=2, l=2048, d_model=1024, h=16, fd=16, hd=64
#define NH 16
#define FD 16
#define HD 64
#define BATCH 2
#define SEQ 2048
#define DM 1024
#define ROWS (BATCH * SEQ)   // 4096 token rows
#define CHUNK 128
#define NCH (SEQ / CHUNK)    // 16 chunks per sequence
#define NBH (BATCH * NH)     // 32 (b,h) pairs

typedef __hip_bfloat16 bf16;
typedef __attribute__((ext_vector_type(8))) short short8;  // 8 bf16 (MFMA A/B frag)
typedef __attribute__((ext_vector_type(4))) float f32x4;   // MFMA C/D frag

__device__ inline float bfbits(unsigned int h) {
  union { unsigned int u; float f; } c; c.u = h << 16; return c.f;
}
__device__ inline unsigned short f2bf(float x) {
  bf16 h = __float2bfloat16(x);
  return *(unsigned short*)&h;
}

// Flexible 8-element f32 fetch: idx must be a multiple of 8.
__device__ inline void load8(const void* src, size_t idx, int isf32, float* out) {
  if (isf32) {
    const float* p = (const float*)src + idx;
    float4 a = *(const float4*)p;
    float4 b = *(const float4*)(p + 4);
    out[0] = a.x; out[1] = a.y; out[2] = a.z; out[3] = a.w;
    out[4] = b.x; out[5] = b.y; out[6] = b.z; out[7] = b.w;
  } else {
    const uint4 w = *(const uint4*)((const unsigned short*)src + idx);
    out[0] = bfbits(w.x & 0xffffu); out[1] = bfbits(w.x >> 16);
    out[2] = bfbits(w.y & 0xffffu); out[3] = bfbits(w.y >> 16);
    out[4] = bfbits(w.z & 0xffffu); out[5] = bfbits(w.z >> 16);
    out[6] = bfbits(w.w & 0xffffu); out[7] = bfbits(w.w >> 16);
  }
}

// Async global->LDS, 16 bytes/lane. LDS dest is wave-uniform base + lane*16.
__device__ inline void gload16(const void* g, void* l) {
  __builtin_amdgcn_global_load_lds(
      (const __attribute__((address_space(1))) unsigned int*)g,
      (__attribute__((address_space(3))) unsigned int*)l, 16, 0, 0);
}

// ---------------------------------------------------------------------------
// Dtype detection (flag=1 means f32): low-16-bit-as-bf16 exponent statistic.
// ---------------------------------------------------------------------------
__global__ __launch_bounds__(256) void detect_dtype(const unsigned int* __restrict__ w,
                                                    int* __restrict__ flag) {
  __shared__ int red[256];
  int cnt = 0;
  for (int i = threadIdx.x; i < 4096; i += 256) {
    unsigned int e = (w[i] >> 7) & 0xFFu;
    cnt += (e >= 0x90u) ? 1 : 0;
  }
  red[threadIdx.x] = cnt;
  __syncthreads();
  for (int s = 128; s > 0; s >>= 1) {
    if (threadIdx.x < s) red[threadIdx.x] += red[threadIdx.x + s];
    __syncthreads();
  }
  if (threadIdx.x == 0) *flag = (red[0] > 64) ? 1 : 0;
}

// ---------------------------------------------------------------------------
// Combined q+k projection GEMM, split-K-in-block. C[4096,256] x2, f32 out.
// ACCURACY-CRITICAL: feeds z = 1/(q.cumsum(k)+eps); absmax 384 is the np-f32
// reference's own error floor. Every f32 group-of-4 (kt asc, kk 4-groups,
// j asc) is BIT-IDENTICAL to rounds 4-7; only the f64 accumulator is split
// at the K=512 boundary (group-aligned) and re-associated at the end —
// f64 reassociation error ~1e-16 rel, invisible at bf16 output ulp.
// Round-7 lesson: VALU/SIMD is invariant (~55us) and LDS floor ~61us; the
// 8x4 fat tile (1.5 B/MAC) previously forced 1 wave/SIMD (no overlap ->
// 132us serialized). Fix: TWO 128-thread k-halves per block, each doing the
// full 64x64 tile with 8x4 micro over K/2 -> 2 waves/SIMD WITH the fat tile;
// f64 partials combined through LDS (reusing the staging buffer).
// BM=BN=64, BK=32, grid 64x8 = 512 blocks (2/CU).
// ---------------------------------------------------------------------------
__global__ __launch_bounds__(256, 2) void gemm_qk5(const void* __restrict__ A,
                                                   const void* __restrict__ Wq,
                                                   const void* __restrict__ Wk,
                                                   const int* __restrict__ flagp,
                                                   float* __restrict__ qf,
                                                   float* __restrict__ kf) {
  const int isf32 = *flagp;
  __shared__ float smem[9216];  // As[2] (64x36) + Bs[2] (64x36) = 36.9 KB
  const int tid = threadIdx.x;
  const int h = tid >> 7;          // k-half: 0 -> [0,512), 1 -> [512,1024)
  const int ltid = tid & 127;
  float* As = smem + h * 2304;
  float* Bs = smem + 4608 + h * 2304;
  const int m0 = blockIdx.x * 64;
  const int isK = blockIdx.y >> 2;           // y in [0,8): 0-3 q, 4-7 k
  const int n0 = (blockIdx.y & 3) * 64;
  const void* B = isK ? Wk : Wq;
  float* C = isK ? kf : qf;
  const int tx = ltid & 7;                   // 8 m-rows, stride 8
  const int ty = ltid >> 3;                  // 16 n-groups of 4
  const int lm = ltid >> 1, lcH = (ltid & 1) * 16;  // loader: 64 rows x 2 halves
  const int kbase = h * 512;
  double dacc[8][4];
#pragma unroll
  for (int i = 0; i < 8; ++i)
#pragma unroll
    for (int n = 0; n < 4; ++n) dacc[i][n] = 0.0;

  float av[16], bv[16];
  load8(A, (size_t)(m0 + lm) * DM + kbase + lcH, isf32, &av[0]);
  load8(A, (size_t)(m0 + lm) * DM + kbase + lcH + 8, isf32, &av[8]);
  load8(B, (size_t)(n0 + lm) * DM + kbase + lcH, isf32, &bv[0]);
  load8(B, (size_t)(n0 + lm) * DM + kbase + lcH + 8, isf32, &bv[8]);

  for (int t = 0; t < 16; ++t) {
    __syncthreads();  // previous tile's LDS reads complete
    *(float4*)&As[lm * 36 + lcH] = *(float4*)&av[0];
    *(float4*)&As[lm * 36 + lcH + 4] = *(float4*)&av[4];
    *(float4*)&As[lm * 36 + lcH + 8] = *(float4*)&av[8];
    *(float4*)&As[lm * 36 + lcH + 12] = *(float4*)&av[12];
    *(float4*)&Bs[lm * 36 + lcH] = *(float4*)&bv[0];
    *(float4*)&Bs[lm * 36 + lcH + 4] = *(float4*)&bv[4];
    *(float4*)&Bs[lm * 36 + lcH + 8] = *(float4*)&bv[8];
    *(float4*)&Bs[lm * 36 + lcH + 12] = *(float4*)&bv[12];
    __syncthreads();
    if (t < 15) {  // register prefetch of next tile (hidden under compute)
      int kt = kbase + (t + 1) * 32;
      load8(A, (size_t)(m0 + lm) * DM + kt + lcH, isf32, &av[0]);
      load8(A, (size_t)(m0 + lm) * DM + kt + lcH + 8, isf32, &av[8]);
      load8(B, (size_t)(n0 + lm) * DM + kt + lcH, isf32, &bv[0]);
      load8(B, (size_t)(n0 + lm) * DM + kt + lcH + 8, isf32, &bv[8]);
    }
    for (int kk = 0; kk < 32; kk += 4) {
      float4 ar[8], br[4];
#pragma unroll
      for (int i = 0; i < 8; ++i) ar[i] = *(const float4*)&As[(tx + 8 * i) * 36 + kk];
#pragma unroll
      for (int n = 0; n < 4; ++n) br[n] = *(const float4*)&Bs[(ty * 4 + n) * 36 + kk];
      float facc[8][4] = {};
#pragma unroll
      for (int j = 0; j < 4; ++j) {
#pragma unroll
        for (int i = 0; i < 8; ++i) {
          float a = ((const float*)&ar[i])[j];
#pragma unroll
          for (int n = 0; n < 4; ++n)
            facc[i][n] += a * ((const float*)&br[n])[j];
        }
      }
#pragma unroll
      for (int i = 0; i < 8; ++i)
#pragma unroll
        for (int n = 0; n < 4; ++n) dacc[i][n] += (double)facc[i][n];
    }
  }

  // Combine the two k-halves' f64 partials through LDS (reuse staging buf).
  double* dbl = (double*)smem;  // 4608 doubles avail, need 128*32 = 4096
  __syncthreads();  // all LDS tile reads done before aliasing
  if (h == 1) {
#pragma unroll
    for (int i = 0; i < 8; ++i)
#pragma unroll
      for (int n = 0; n < 4; ++n) dbl[ltid * 32 + i * 4 + n] = dacc[i][n];
  }
  __syncthreads();
  if (h == 0) {
#pragma unroll
    for (int i = 0; i < 8; ++i) {
#pragma unroll
      for (int n = 0; n < 4; ++n) dacc[i][n] += dbl[ltid * 32 + i * 4 + n];
      int row = m0 + tx + 8 * i;
      float4 o;
      o.x = (float)dacc[i][0]; o.y = (float)dacc[i][1];
      o.z = (float)dacc[i][2]; o.w = (float)dacc[i][3];
      *(float4*)&C[(size_t)row * 256 + n0 + ty * 4] = o;
    }
  }
}

// ---------------------------------------------------------------------------
// MFMA GEMM w/ LDS staging (m97 structure): C[4096,1024] = A @ B^T, K=1024.
// Block tile 128x64, BK=32, 4 waves (each 64 rows x 32 cols), single LDS
// buffer + 2 barriers, global_load_lds width=16 (bf16 fast path).
// MODE 0: v-proj (A flex dtype, C bf16). MODE 1: o-proj (A bf16, C flex).
// ---------------------------------------------------------------------------
template <int MODE>
__global__ __launch_bounds__(256) void gemm_mfma(const void* __restrict__ Ap,
                                                 const void* __restrict__ Bp,
                                                 const int* __restrict__ flagp,
                                                 void* __restrict__ Cp) {
  const int isf32 = *flagp;
  const int aF32 = (MODE == 0) ? isf32 : 0;
  const int bF32 = isf32;
  __shared__ unsigned short As[128 * 32];  // row-major, 32 bf16 (64B) per row
  __shared__ unsigned short Bs[64 * 32];
  const int tid = threadIdx.x;
  const int wave = tid >> 6, lane = tid & 63;
  const int m0 = blockIdx.x * 128, n0 = blockIdx.y * 64;
  const int lrow = lane >> 2, lch = (lane & 3) * 8;  // loader: 16 rows x 4 chunks
  const int wm = wave >> 1, wn = wave & 1;           // wave -> 64x32 subtile
  const int mlane = lane & 15, kgrp = lane >> 4;
  const unsigned short* Ab = (const unsigned short*)Ap;
  const unsigned short* Bb = (const unsigned short*)Bp;
  f32x4 acc[4][2];
#pragma unroll
  for (int t = 0; t < 4; ++t)
#pragma unroll
    for (int u = 0; u < 2; ++u) acc[t][u] = (f32x4){0.f, 0.f, 0.f, 0.f};

  for (int k0 = 0; k0 < DM; k0 += 32) {
    __syncthreads();  // previous iter's frag reads done before overwrite
    if (!aF32) {
      const int r0 = wave * 32;
#pragma unroll
      for (int j = 0; j < 2; ++j) {
        const void* g = Ab + (size_t)(m0 + r0 + j * 16 + lrow) * DM + k0 + lch;
        gload16(g, &As[(r0 + j * 16) * 32]);  // wave-uniform LDS base
      }
    } else {
      for (int c = tid; c < 512; c += 256) {
        int r = c >> 2, cc = (c & 3) * 8;
        float v8[8];
        load8(Ap, (size_t)(m0 + r) * DM + k0 + cc, 1, v8);
        unsigned int w[4];
#pragma unroll
        for (int g2 = 0; g2 < 4; ++g2)
          w[g2] = (unsigned)f2bf(v8[2 * g2]) | ((unsigned)f2bf(v8[2 * g2 + 1]) << 16);
        *(uint4*)&As[r * 32 + cc] = *(uint4*)w;
      }
    }
    if (!bF32) {
      const void* g = Bb + (size_t)(n0 + wave * 16 + lrow) * DM + k0 + lch;
      gload16(g, &Bs[(wave * 16) * 32]);
    } else {
      {
        int c = tid;  // 256 chunks, one per thread
        int r = c >> 2, cc = (c & 3) * 8;
        float v8[8];
        load8(Bp, (size_t)(n0 + r) * DM + k0 + cc, 1, v8);
        unsigned int w[4];
#pragma unroll
        for (int g2 = 0; g2 < 4; ++g2)
          w[g2] = (unsigned)f2bf(v8[2 * g2]) | ((unsigned)f2bf(v8[2 * g2 + 1]) << 16);
        *(uint4*)&Bs[r * 32 + cc] = *(uint4*)w;
      }
    }
    __syncthreads();  // drains vmcnt (global_load_lds) + lgkmcnt

    short8 af[4], bfr[2];
#pragma unroll
    for (int t = 0; t < 4; ++t)
      af[t] = *(const short8*)&As[(wm * 64 + t * 16 + mlane) * 32 + kgrp * 8];
#pragma unroll
    for (int u = 0; u < 2; ++u)
      bfr[u] = *(const short8*)&Bs[(wn * 32 + u * 16 + mlane) * 32 + kgrp * 8];
#pragma unroll
    for (int t = 0; t < 4; ++t)
#pragma unroll
      for (int u = 0; u < 2; ++u)
        acc[t][u] = __builtin_amdgcn_mfma_f32_16x16x32_bf16(af[t], bfr[u], acc[t][u], 0, 0, 0);
  }

#pragma unroll
  for (int t = 0; t < 4; ++t)
#pragma unroll
    for (int u = 0; u < 2; ++u)
#pragma unroll
      for (int r = 0; r < 4; ++r) {
        int row = m0 + wm * 64 + t * 16 + kgrp * 4 + r;
        int col = n0 + wn * 32 + u * 16 + mlane;
        float v = acc[t][u][r];
        if (MODE == 0) {
          ((unsigned short*)Cp)[(size_t)row * DM + col] = f2bf(v);
        } else if (isf32) {
          ((float*)Cp)[(size_t)row * DM + col] = v;
        } else {
          ((unsigned short*)Cp)[(size_t)row * DM + col] = f2bf(v);
        }
      }
}

// ---------------------------------------------------------------------------
// attn_intra: per (b,h,chunk): causal intra-chunk y (bf16 out), chunk state
// S_c = k^T v (f32), chunk k-sum (f64). Grid = 512, 256 threads.
// ---------------------------------------------------------------------------
__global__ __launch_bounds__(256) void attn_intra(const float* __restrict__ qf,
                                                  const float* __restrict__ kf,
                                                  const unsigned short* __restrict__ vfb,
                                                  unsigned short* __restrict__ yib,
                                                  float* __restrict__ Sc,
                                                  double* __restrict__ Kc) {
  __shared__ float qc[CHUNK][20];
  __shared__ float kc[CHUNK][20];
  __shared__ float vc[CHUNK][68];
  const int bh = blockIdx.x >> 4;
  const int c = blockIdx.x & 15;
  const int b = bh >> 4, h = bh & 15;
  const int bl = c * CHUNK;
  const int tid = threadIdx.x;

  for (int idx = tid; idx < CHUNK * FD / 4; idx += 256) {
    int r = idx >> 2, f4 = (idx & 3) * 4;
    size_t g = ((size_t)(b * SEQ + bl + r)) * (NH * FD) + h * FD + f4;
    *(float4*)&qc[r][f4] = *(const float4*)&qf[g];
    *(float4*)&kc[r][f4] = *(const float4*)&kf[g];
  }
  for (int idx = tid; idx < CHUNK * HD / 8; idx += 256) {
    int r = idx >> 3, e8 = (idx & 7) * 8;
    uint4 w = *(const uint4*)&vfb[((size_t)(b * SEQ + bl + r)) * (NH * HD) + h * HD + e8];
    vc[r][e8 + 0] = bfbits(w.x & 0xffffu); vc[r][e8 + 1] = bfbits(w.x >> 16);
    vc[r][e8 + 2] = bfbits(w.y & 0xffffu); vc[r][e8 + 3] = bfbits(w.y >> 16);
    vc[r][e8 + 4] = bfbits(w.z & 0xffffu); vc[r][e8 + 5] = bfbits(w.z >> 16);
    vc[r][e8 + 6] = bfbits(w.w & 0xffffu); vc[r][e8 + 7] = bfbits(w.w >> 16);
  }
  __syncthreads();

  const int p = tid >> 2;
  const int n0 = 2 * p, n1 = 2 * p + 1;
  const int e0 = (tid & 3) * 16;
  float q0r[16], q1r[16];
#pragma unroll
  for (int d = 0; d < 16; ++d) { q0r[d] = qc[n0][d]; q1r[d] = qc[n1][d]; }
  float y0[16], y1[16];
#pragma unroll
  for (int e = 0; e < 16; ++e) { y0[e] = 0.f; y1[e] = 0.f; }

  for (int m = 0; m <= n1; ++m) {
    float kd[16], vv[16];
#pragma unroll
    for (int d = 0; d < 16; ++d) kd[d] = kc[m][d];
#pragma unroll
    for (int e = 0; e < 16; ++e) vv[e] = vc[m][e0 + e];
    float d0 = 0.f, d1 = 0.f;
#pragma unroll
    for (int d = 0; d < 16; ++d) { d0 += q0r[d] * kd[d]; d1 += q1r[d] * kd[d]; }
    if (m > n0) d0 = 0.f;  // causal mask (only the m==n1 step)
#pragma unroll
    for (int e = 0; e < 16; ++e) { y0[e] += d0 * vv[e]; y1[e] += d1 * vv[e]; }
  }
  const size_t ybase = (size_t)bh * SEQ + bl;
  {
    unsigned int w[4];
#pragma unroll
    for (int g = 0; g < 4; ++g)
      w[g] = (unsigned)f2bf(y0[2 * g]) | ((unsigned)f2bf(y0[2 * g + 1]) << 16);
    *(uint4*)&yib[(ybase + n0) * HD + e0] = *(uint4*)w;
#pragma unroll
    for (int g = 0; g < 4; ++g)
      w[g] = (unsigned)f2bf(y0[8 + 2 * g]) | ((unsigned)f2bf(y0[9 + 2 * g]) << 16);
    *(uint4*)&yib[(ybase + n0) * HD + e0 + 8] = *(uint4*)w;
#pragma unroll
    for (int g = 0; g < 4; ++g)
      w[g] = (unsigned)f2bf(y1[2 * g]) | ((unsigned)f2bf(y1[2 * g + 1]) << 16);
    *(uint4*)&yib[(ybase + n1) * HD + e0] = *(uint4*)w;
#pragma unroll
    for (int g = 0; g < 4; ++g)
      w[g] = (unsigned)f2bf(y1[8 + 2 * g]) | ((unsigned)f2bf(y1[9 + 2 * g]) << 16);
    *(uint4*)&yib[(ybase + n1) * HD + e0 + 8] = *(uint4*)w;
  }

  float* Scp = Sc + ((size_t)bh * NCH + c) * (FD * HD);
  for (int idx = tid; idx < FD * HD; idx += 256) {
    int d = idx >> 6, e = idx & 63;
    float s = 0.f;
    for (int m = 0; m < CHUNK; ++m) s += kc[m][d] * vc[m][e];
    Scp[idx] = s;
  }
  if (tid < FD) {
    double ks = 0.0;
    for (int m = 0; m < CHUNK; ++m) ks += (double)kc[m][tid];
    Kc[((size_t)bh * NCH + c) * FD + tid] = ks;
  }
}

// Exclusive prefix over chunks of S_c (f32) and Kc (f64). Grid = NBH = 32.
__global__ __launch_bounds__(256) void scan_states(float* __restrict__ Sc,
                                                   double* __restrict__ Kc) {
  const int bh = blockIdx.x;
  const int tid = threadIdx.x;
  float4 acc = make_float4(0.f, 0.f, 0.f, 0.f);
  size_t base = (size_t)bh * NCH * (FD * HD) + (size_t)tid * 4;
  for (int c = 0; c < NCH; ++c) {
    float4* p = (float4*)(Sc + base + (size_t)c * (FD * HD));
    float4 v = *p;
    *p = acc;
    acc.x += v.x; acc.y += v.y; acc.z += v.z; acc.w += v.w;
  }
  if (tid < FD) {
    double a = 0.0;
    for (int c = 0; c < NCH; ++c) {
      size_t i = ((size_t)bh * NCH + c) * FD + tid;
      double t = Kc[i];
      Kc[i] = a;
      a += t;
    }
  }
}

// ---------------------------------------------------------------------------
// attn_finish: y = (y_intra + q @ S_prev) * z, z = 1/(q.cumsum(k)+eps) in f64.
// Emits bf16 y in [b,l,h*hd] layout. Grid = 512.
// ---------------------------------------------------------------------------
__global__ __launch_bounds__(256) void attn_finish(const float* __restrict__ qf,
                                                   const float* __restrict__ kf,
                                                   const unsigned short* __restrict__ yib,
                                                   const float* __restrict__ Sc,
                                                   const double* __restrict__ Kc,
                                                   unsigned short* __restrict__ yob) {
  __shared__ float qc[CHUNK][20];
  __shared__ float kc[CHUNK][20];
  __shared__ float Sp[FD][HD];
  __shared__ double cs[CHUNK][17];
  __shared__ double zl[CHUNK];
  __shared__ double ksp[FD];
  const int bh = blockIdx.x >> 4;
  const int c = blockIdx.x & 15;
  const int b = bh >> 4, h = bh & 15;
  const int bl = c * CHUNK;
  const int tid = threadIdx.x;

  for (int idx = tid; idx < CHUNK * FD / 4; idx += 256) {
    int r = idx >> 2, f4 = (idx & 3) * 4;
    size_t g = ((size_t)(b * SEQ + bl + r)) * (NH * FD) + h * FD + f4;
    *(float4*)&qc[r][f4] = *(const float4*)&qf[g];
    *(float4*)&kc[r][f4] = *(const float4*)&kf[g];
  }
  const float* Scp = Sc + ((size_t)bh * NCH + c) * (FD * HD);
  for (int idx = tid; idx < FD * HD / 4; idx += 256) {
    int d = idx >> 4, e4 = (idx & 15) * 4;
    *(float4*)&Sp[d][e4] = *(const float4*)&Scp[(size_t)d * HD + e4];
  }
  if (tid < FD) ksp[tid] = Kc[((size_t)bh * NCH + c) * FD + tid];
  __syncthreads();

  if (tid < FD) {
    double run = ksp[tid];
    for (int m = 0; m < CHUNK; ++m) {
      run += (double)kc[m][tid];
      cs[m][tid] = run;
    }
  }
  __syncthreads();
  if (tid < CHUNK) {
    double dn = 0.0;
#pragma unroll
    for (int d = 0; d < 16; ++d) dn += (double)qc[tid][d] * cs[tid][d];
    zl[tid] = 1.0 / (dn + 1e-12);
  }
  __syncthreads();

  for (int idx = tid; idx < CHUNK * HD / 8; idx += 256) {
    int n = idx >> 3, e8 = (idx & 7) * 8;
    uint4 w = *(const uint4*)&yib[((size_t)bh * SEQ + bl + n) * HD + e8];
    float yv[8] = {bfbits(w.x & 0xffffu), bfbits(w.x >> 16),
                   bfbits(w.y & 0xffffu), bfbits(w.y >> 16),
                   bfbits(w.z & 0xffffu), bfbits(w.z >> 16),
                   bfbits(w.w & 0xffffu), bfbits(w.w >> 16)};
    double z = zl[n];
    unsigned int o[4];
#pragma unroll
    for (int jp = 0; jp < 4; ++jp) {
      int e = e8 + 2 * jp;
      float i0 = 0.f, i1 = 0.f;
#pragma unroll
      for (int d = 0; d < 16; ++d) {
        i0 += qc[n][d] * Sp[d][e];
        i1 += qc[n][d] * Sp[d][e + 1];
      }
      float r0 = (float)(((double)(yv[2 * jp] + i0)) * z);
      float r1 = (float)(((double)(yv[2 * jp + 1] + i1)) * z);
      o[jp] = (unsigned)f2bf(r0) | ((unsigned)f2bf(r1) << 16);
    }
    *(uint4*)&yob[((size_t)(b * SEQ + bl + n)) * (NH * HD) + h * HD + e8] = *(uint4*)o;
  }
}

extern "C" void kernel_launch(void* const* d_in, const int* in_sizes, int n_in,
                              void* d_out, int out_size, void* d_ws, size_t ws_size,
                              hipStream_t stream) {
  (void)in_sizes; (void)n_in; (void)out_size; (void)ws_size;
  const void* hs = d_in[0];
  const void* Wq = d_in[1];
  const void* Wk = d_in[2];
  const void* Wv = d_in[3];
  const void* Wo = d_in[4];

  // workspace (26.1 MB, proven safe; 42 MB NaN'd in round 1 — do not grow):
  // qf 4M | kf 4M | vfb/yob 8M (alias; v dead after attn_intra) | yib 8M |
  // Sc 2M | Kc 64K | flag
  char* ws = (char*)d_ws;
  float* qf = (float*)(ws);
  float* kf = (float*)(ws + (4u << 20));
  unsigned short* vfb = (unsigned short*)(ws + (8u << 20));
  unsigned short* yob = vfb;
  unsigned short* yib = (unsigned short*)(ws + (16u << 20));
  float* Sc = (float*)(ws + (24u << 20));
  double* Kc = (double*)(ws + (26u << 20));
  int* flag = (int*)(ws + (26u << 20) + 65536);

  detect_dtype<<<1, 256, 0, stream>>>((const unsigned int*)hs, flag);
  gemm_qk5<<<dim3(ROWS / 64, 8), 256, 0, stream>>>(hs, Wq, Wk, flag, qf, kf);
  gemm_mfma<0><<<dim3(ROWS / 128, 1024 / 64), 256, 0, stream>>>(hs, Wv, flag, vfb);
  attn_intra<<<NBH * NCH, 256, 0, stream>>>(qf, kf, vfb, yib, Sc, Kc);
  scan_states<<<NBH, 256, 0, stream>>>(Sc, Kc);
  attn_finish<<<NBH * NCH, 256, 0, stream>>>(qf, kf, yib, Sc, Kc, yob);
  gemm_mfma<1><<<dim3(ROWS / 128, 1024 / 64), 256, 0, stream>>>(yob, Wo, flag, d_out);
}